// Round 9
// baseline (381.499 us; speedup 1.0000x reference)
//
#include <hip/hip_runtime.h>
#include <hip/hip_bf16.h>
#include <math.h>

#define IN_CH   128
#define HC      256   // HEADS*OUT_C
#define OUT_C   64
#define CSTR    64    // fixed csr stride per (node,hop); P(deg>64)~1e-17

typedef unsigned short ushort_t;
typedef __attribute__((ext_vector_type(2))) float v2f;
typedef __attribute__((ext_vector_type(4))) float v4f;
typedef __attribute__((ext_vector_type(8))) short bf16x8;   // 8 bf16 (4 VGPRs)

__device__ __forceinline__ ushort_t f2bf_rne(float f) {
    unsigned u = __float_as_uint(f);
    unsigned r = (u + 0x7FFFu + ((u >> 16) & 1u)) >> 16;
    return (ushort_t)r;
}
__device__ __forceinline__ v2f bfpair(unsigned u) {
    v2f r;
    r.x = __uint_as_float(u << 16);
    r.y = __uint_as_float(u & 0xffff0000u);
    return r;
}
__device__ __forceinline__ v2f vmax0(v2f a) {
    v2f r;
    r.x = fmaxf(a.x, 0.f);
    r.y = fmaxf(a.y, 0.f);
    return r;
}

// ---- nontemporal helpers: ONLY for data not re-read by a later kernel ----
__device__ __forceinline__ float4 ntld4(const float* p) {
    v4f t = __builtin_nontemporal_load((const v4f*)p);
    return make_float4(t.x, t.y, t.z, t.w);
}
__device__ __forceinline__ int ntldi(const int* p) {
    return __builtin_nontemporal_load(p);
}
__device__ __forceinline__ void ntst4(float* p, float4 v) {
    v4f t = {v.x, v.y, v.z, v.w};
    __builtin_nontemporal_store(t, (v4f*)p);
}

// ---- 16-lane (DPP-row) sum via row_ror rotations: pure VALU, no LDS pipe.
#define DPP_ROR_ADD(x, N)                                                   \
    (x) += __uint_as_float(__builtin_amdgcn_update_dpp(                     \
        0, __float_as_uint(x), 0x120 + (N), 0xF, 0xF, true))

__device__ __forceinline__ float rowsum16(float x) {
    DPP_ROR_ADD(x, 8);
    DPP_ROR_ADD(x, 4);
    DPP_ROR_ADD(x, 2);
    DPP_ROR_ADD(x, 1);
    return x;
}

__device__ __forceinline__ bf16x8 ldbf(const uint4* p) {
    union { uint4 u; bf16x8 v; } t;
    t.u = *p;
    return t.v;
}

// ===========================================================================
// HS: mixed grid — [0,GH) FUSED hist+scatter both hops (fixed-stride csr:
// slot = dst*64 + atomicAdd(deg), no scan/rank/offs needed) || x-split-pack
// || W-split-pack. rank<64 guard: overflow is dropped, never corrupts.
// ===========================================================================
__global__ __launch_bounds__(256) void k_hs(const float* __restrict__ x,
                                            const float* __restrict__ Wl,
                                            const float* __restrict__ Wr0,
                                            const float* __restrict__ Wr1,
                                            uint4* __restrict__ xAh,
                                            uint4* __restrict__ xAl,
                                            uint4* __restrict__ WBh,
                                            uint4* __restrict__ WBl,
                                            int n, int GH, int gPX,
                                            const int* __restrict__ src1,
                                            const int* __restrict__ dst1, int E1,
                                            const int* __restrict__ src2,
                                            const int* __restrict__ dst2, int E2,
                                            int* __restrict__ deg,
                                            int* __restrict__ csr) {
    const int bx = blockIdx.x;
    if (bx < GH) {
        const int Et = E1 + E2;
        for (int i = bx * 256 + threadIdx.x; i < Et; i += GH * 256) {
            int d, s;
            if (i < E1) {
                d = ntldi(dst1 + i);
                s = ntldi(src1 + i);
            } else {
                const int j2 = i - E1;
                d = n + ntldi(dst2 + j2);
                s = ntldi(src2 + j2);
            }
            const int r = atomicAdd(&deg[d], 1);
            if (r < CSTR) csr[(d << 6) + r] = s << 9;
        }
        return;
    }
    const int t = bx - GH;
    float v[8];
    ushort_t h[8], l[8];
    if (t < gPX) {
        const int di  = t * 256 + threadIdx.x;        // sequential store index
        const int row = ((di >> 8) << 4) | (di & 15);
        const int ko  = ((di >> 4) & 3) | (((di >> 6) & 3) << 2);
        float4 v0 = make_float4(0.f, 0.f, 0.f, 0.f), v1 = v0;
        if (row < n) {
            const float4* xp = (const float4*)(x + (size_t)row * IN_CH + ko * 8);
            v0 = xp[0];
            v1 = xp[1];
        }
        v[0] = v0.x; v[1] = v0.y; v[2] = v0.z; v[3] = v0.w;
        v[4] = v1.x; v[5] = v1.y; v[6] = v1.z; v[7] = v1.w;
#pragma unroll
        for (int j = 0; j < 8; ++j) {
            h[j] = f2bf_rne(v[j]);
            l[j] = f2bf_rne(v[j] - __uint_as_float((unsigned)h[j] << 16));
        }
        uint4 ph, pl;
        ph.x = (unsigned)h[0] | ((unsigned)h[1] << 16);
        ph.y = (unsigned)h[2] | ((unsigned)h[3] << 16);
        ph.z = (unsigned)h[4] | ((unsigned)h[5] << 16);
        ph.w = (unsigned)h[6] | ((unsigned)h[7] << 16);
        pl.x = (unsigned)l[0] | ((unsigned)l[1] << 16);
        pl.y = (unsigned)l[2] | ((unsigned)l[3] << 16);
        pl.z = (unsigned)l[4] | ((unsigned)l[5] << 16);
        pl.w = (unsigned)l[6] | ((unsigned)l[7] << 16);
        xAh[di] = ph;
        xAl[di] = pl;
    } else {
        const int idx = (t - gPX) * 256 + threadIdx.x;   // [0, 3*4*16*64)
        const int lane = idx & 63;
        const int f    = (idx >> 6) & 15;
        const int c    = (idx >> 10) & 3;
        const int w    = idx >> 12;
        if (w >= 3) return;
        const float* Wp = (w == 0) ? Wl : ((w == 1) ? Wr0 : Wr1);
        const int col = f * 16 + (lane & 15);
        const int k0  = c * 32 + (lane >> 4) * 8;
#pragma unroll
        for (int j = 0; j < 8; ++j) {
            v[j] = Wp[(size_t)(k0 + j) * HC + col];
            h[j] = f2bf_rne(v[j]);
            l[j] = f2bf_rne(v[j] - __uint_as_float((unsigned)h[j] << 16));
        }
        uint4 ph, pl;
        ph.x = (unsigned)h[0] | ((unsigned)h[1] << 16);
        ph.y = (unsigned)h[2] | ((unsigned)h[3] << 16);
        ph.z = (unsigned)h[4] | ((unsigned)h[5] << 16);
        ph.w = (unsigned)h[6] | ((unsigned)h[7] << 16);
        pl.x = (unsigned)l[0] | ((unsigned)l[1] << 16);
        pl.y = (unsigned)l[2] | ((unsigned)l[3] << 16);
        pl.z = (unsigned)l[4] | ((unsigned)l[5] << 16);
        pl.w = (unsigned)l[6] | ((unsigned)l[7] << 16);
        WBh[idx] = ph;
        WBl[idx] = pl;
    }
}

// ===========================================================================
// Pure MFMA GEMM x @ {Wl, Wr0, Wr1} (split-bf16, 3-term).
// XCD-congruent tile mapping (3 wsel-blocks of a tile land on one XCD/L2).
// ===========================================================================
__global__ __launch_bounds__(256) void k_gemm3(const uint4* __restrict__ xAh,
                                               const uint4* __restrict__ xAl,
                                               const uint4* __restrict__ WBh,
                                               const uint4* __restrict__ WBl,
                                               ushort_t* __restrict__ xlh,
                                               float* __restrict__ xr0,
                                               float* __restrict__ xr1,
                                               int n, int gT) {
    const int t = blockIdx.x;
    const int gT8 = (gT / 8) * 8;       // tiles covered by full 24-windows
    int tile, wsel;
    if (t < 3 * gT8) {
        const int k = t / 24;
        const int r = t - k * 24;
        tile = k * 8 + (r & 7);
        wsel = r >> 3;
    } else {
        const int u = t - 3 * gT8;
        tile = gT8 + u / 3;
        wsel = u - (u / 3) * 3;
    }

    const int lane = threadIdx.x & 63;
    const int wave = __builtin_amdgcn_readfirstlane((int)(threadIdx.x >> 6));

    v4f acc[4][4];
#pragma unroll
    for (int g = 0; g < 4; ++g)
#pragma unroll
        for (int f = 0; f < 4; ++f) acc[g][f] = (v4f){0.f, 0.f, 0.f, 0.f};

    const uint4* Bh = WBh + (size_t)wsel * 4096;
    const uint4* Bl = WBl + (size_t)wsel * 4096;
    const int g0 = tile * 4;

    for (int c = 0; c < 4; ++c) {
        bf16x8 ah[4], al[4], bh[4], bl[4];
#pragma unroll
        for (int g = 0; g < 4; ++g) {
            const int ai = ((g0 + g) * 4 + c) * 64 + lane;
            ah[g] = ldbf(xAh + ai);
            al[g] = ldbf(xAl + ai);
        }
#pragma unroll
        for (int f = 0; f < 4; ++f) {
            const int bi = (c * 16 + wave * 4 + f) * 64 + lane;
            bh[f] = ldbf(Bh + bi);
            bl[f] = ldbf(Bl + bi);
        }
#pragma unroll
        for (int g = 0; g < 4; ++g)
#pragma unroll
            for (int f = 0; f < 4; ++f) {
                acc[g][f] = __builtin_amdgcn_mfma_f32_16x16x32_bf16(ah[g], bh[f], acc[g][f], 0, 0, 0);
                acc[g][f] = __builtin_amdgcn_mfma_f32_16x16x32_bf16(ah[g], bl[f], acc[g][f], 0, 0, 0);
                acc[g][f] = __builtin_amdgcn_mfma_f32_16x16x32_bf16(al[g], bh[f], acc[g][f], 0, 0, 0);
            }
    }

    const int colB = wave * 64 + (lane & 15);
    const int rowB = tile * 64 + ((lane >> 4) << 2);
    if (wsel == 0) {
#pragma unroll
        for (int g = 0; g < 4; ++g)
#pragma unroll
            for (int f = 0; f < 4; ++f) {
                const int col = colB + f * 16;
#pragma unroll
                for (int r = 0; r < 4; ++r) {
                    const int row = rowB + g * 16 + r;
                    if (row < n) xlh[(size_t)row * HC + col] = f2bf_rne(acc[g][f][r]);
                }
            }
    } else {
        float* o = (wsel == 1) ? xr0 : xr1;
#pragma unroll
        for (int g = 0; g < 4; ++g)
#pragma unroll
            for (int f = 0; f < 4; ++f) {
                const int col = colB + f * 16;
#pragma unroll
                for (int r = 0; r < 4; ++r) {
                    const int row = rowB + g * 16 + r;
                    if (row < n) o[(size_t)row * HC + col] = acc[g][f][r];   // cached
                }
            }
    }
}

// ===========================================================================
// BOTH-HOP fused aggregation (R7 inner loop — the explicit double-buffer of
// R8 regressed; compiler's vmcnt scheduling already covers the overlap).
// Fixed-stride csr: s = node<<6, deg clamped to 64, single 64-entry batch
// lane-spread + readlane -> SGPR-base gathers. Both hops' batches prefetched.
// ===========================================================================
__global__ __launch_bounds__(128) void k_aggboth(const ushort_t* __restrict__ xlh,
                                                 const float* __restrict__ xr0,
                                                 const float* __restrict__ xr1,
                                                 const float* __restrict__ att0,
                                                 const float* __restrict__ att1,
                                                 const int* __restrict__ deg,
                                                 const int* __restrict__ csr,
                                                 int n, float* __restrict__ out,
                                                 const float* __restrict__ theta) {
    const int lane = threadIdx.x & 63;
    int node_ = blockIdx.x * 2 + (threadIdx.x >> 6);
    if (node_ >= n) return;
    const int node = __builtin_amdgcn_readfirstlane(node_);

    const float th = theta[0];                       // hoisted scalar load

    const float4 at0 = ((const float4*)att0)[lane];
    const float4 at1 = ((const float4*)att1)[lane];
    const v2f a2_0a = {0.2f * at0.x, 0.2f * at0.y}, a2_0b = {0.2f * at0.z, 0.2f * at0.w};
    const v2f a8_0a = {0.8f * at0.x, 0.8f * at0.y}, a8_0b = {0.8f * at0.z, 0.8f * at0.w};
    const v2f a2_1a = {0.2f * at1.x, 0.2f * at1.y}, a2_1b = {0.2f * at1.z, 0.2f * at1.w};
    const v2f a8_1a = {0.8f * at1.x, 0.8f * at1.y}, a8_1b = {0.8f * at1.z, 0.8f * at1.w};
    const float4 q0 = ntld4(xr0 + (size_t)node * HC + 4 * lane);
    const float4 q1 = ntld4(xr1 + (size_t)node * HC + 4 * lane);
    const v2f x0a = {q0.x, q0.y}, x0b = {q0.z, q0.w};
    const v2f x1a = {q1.x, q1.y}, x1b = {q1.z, q1.w};

    int t0 = deg[node];      t0 = t0 > CSTR ? CSTR : t0;
    int t1 = deg[n + node];  t1 = t1 > CSTR ? CSTR : t1;
    const unsigned s0 = (unsigned)node << 6;
    const unsigned s1 = (unsigned)(n + node) << 6;

    const char* Xc = (const char*)xlh;
    const unsigned laneB = (unsigned)lane * 8u;
    auto gath = [&](unsigned off) -> uint2 {        // off is wave-uniform (SGPR)
        const char* p = Xc + off;                   // s_add -> SGPR base
        return *(const uint2*)(p + laneB);          // s-base + v-offset load
    };

    float l0 = 0.f, l1 = 0.f;
    v2f O0a = {0.f, 0.f}, O0b = {0.f, 0.f};
    v2f O1a = {0.f, 0.f}, O1b = {0.f, 0.f};

    auto proc = [&](uint2 w, const v2f& xa, const v2f& xb,
                    const v2f& a8a, const v2f& a8b,
                    const v2f& a2a, const v2f& a2b, float& l, v2f& Oa, v2f& Ob) {
        v2f ca = bfpair(w.x), cb = bfpair(w.y);
        v2f za = ca + xa, zb = cb + xb;
        v2f t = a2a * za + a2b * zb + a8a * vmax0(za) + a8b * vmax0(zb);
        float part = rowsum16(t.x + t.y);
        float p = __expf(fminf(part, 60.f));
        l += p;
        v2f pp = {p, p};
        Oa = pp * ca + Oa;
        Ob = pp * cb + Ob;
    };
    auto proc0 = [&](uint2 w) { proc(w, x0a, x0b, a8_0a, a8_0b, a2_0a, a2_0b, l0, O0a, O0b); };
    auto proc1 = [&](uint2 w) { proc(w, x1a, x1b, a8_1a, a8_1b, a2_1a, a2_1b, l1, O1a, O1b); };

    // Prefetch BOTH hops' csr batches; latency hides under self-loop proc.
    unsigned vc0 = 0, vc1 = 0;
    if (t0 > 0) vc0 = (unsigned)csr[s0 + lane];
    if (t1 > 0) vc1 = (unsigned)csr[s1 + lane];

    proc0(gath((unsigned)node << 9));               // virtual self loop

    // ---- hop 0 (single batch: t0 <= 64) ----
    {
        int j = 0;
        for (; j + 8 <= t0; j += 8) {
            uint2 g0 = gath((unsigned)__builtin_amdgcn_readlane(vc0, j + 0));
            uint2 g1 = gath((unsigned)__builtin_amdgcn_readlane(vc0, j + 1));
            uint2 g2 = gath((unsigned)__builtin_amdgcn_readlane(vc0, j + 2));
            uint2 g3 = gath((unsigned)__builtin_amdgcn_readlane(vc0, j + 3));
            uint2 g4 = gath((unsigned)__builtin_amdgcn_readlane(vc0, j + 4));
            uint2 g5 = gath((unsigned)__builtin_amdgcn_readlane(vc0, j + 5));
            uint2 g6 = gath((unsigned)__builtin_amdgcn_readlane(vc0, j + 6));
            uint2 g7 = gath((unsigned)__builtin_amdgcn_readlane(vc0, j + 7));
            proc0(g0); proc0(g1); proc0(g2); proc0(g3);
            proc0(g4); proc0(g5); proc0(g6); proc0(g7);
        }
        for (; j + 2 <= t0; j += 2) {
            uint2 g0 = gath((unsigned)__builtin_amdgcn_readlane(vc0, j + 0));
            uint2 g1 = gath((unsigned)__builtin_amdgcn_readlane(vc0, j + 1));
            proc0(g0); proc0(g1);
        }
        if (j < t0) proc0(gath((unsigned)__builtin_amdgcn_readlane(vc0, j)));
    }

    // ---- hop 1 (single batch: t1 <= 64) ----
    {
        int j = 0;
        for (; j + 8 <= t1; j += 8) {
            uint2 g0 = gath((unsigned)__builtin_amdgcn_readlane(vc1, j + 0));
            uint2 g1 = gath((unsigned)__builtin_amdgcn_readlane(vc1, j + 1));
            uint2 g2 = gath((unsigned)__builtin_amdgcn_readlane(vc1, j + 2));
            uint2 g3 = gath((unsigned)__builtin_amdgcn_readlane(vc1, j + 3));
            uint2 g4 = gath((unsigned)__builtin_amdgcn_readlane(vc1, j + 4));
            uint2 g5 = gath((unsigned)__builtin_amdgcn_readlane(vc1, j + 5));
            uint2 g6 = gath((unsigned)__builtin_amdgcn_readlane(vc1, j + 6));
            uint2 g7 = gath((unsigned)__builtin_amdgcn_readlane(vc1, j + 7));
            proc1(g0); proc1(g1); proc1(g2); proc1(g3);
            proc1(g4); proc1(g5); proc1(g6); proc1(g7);
        }
        for (; j + 2 <= t1; j += 2) {
            uint2 g0 = gath((unsigned)__builtin_amdgcn_readlane(vc1, j + 0));
            uint2 g1 = gath((unsigned)__builtin_amdgcn_readlane(vc1, j + 1));
            proc1(g0); proc1(g1);
        }
        if (j < t1) proc1(gath((unsigned)__builtin_amdgcn_readlane(vc1, j)));
    }

    const float inv0 = 0.25f / l0;
    const float inv1 = (l1 > 0.f) ? 0.25f / l1 : 0.f;
    const float sg = 1.f / (1.f + __expf(-th));
    float vx = O0a.x * inv0 + sg * (O1a.x * inv1);
    float vy = O0a.y * inv0 + sg * (O1a.y * inv1);
    float vz = O0b.x * inv0 + sg * (O1b.x * inv1);
    float vw = O0b.y * inv0 + sg * (O1b.y * inv1);
    vx += __shfl_xor(vx, 16); vx += __shfl_xor(vx, 32);
    vy += __shfl_xor(vy, 16); vy += __shfl_xor(vy, 32);
    vz += __shfl_xor(vz, 16); vz += __shfl_xor(vz, 32);
    vw += __shfl_xor(vw, 16); vw += __shfl_xor(vw, 32);

    if (lane < 16) {
        ntst4(out + (size_t)node * OUT_C + 4 * lane, make_float4(vx, vy, vz, vw));
    }
}

// ===========================================================================
// ======================= FALLBACK PATH (old VALU) ==========================
// ===========================================================================
__device__ __forceinline__ void dev_gemm(const float* __restrict__ x,
                                         const float* __restrict__ W,
                                         float* __restrict__ outf,
                                         ushort_t* __restrict__ outh,
                                         int n, int bx) {
    const int tid = threadIdx.x;
    const int c4  = tid & 63;
    const int rg  = __builtin_amdgcn_readfirstlane(tid >> 6);
    const int row0 = bx * 64 + rg * 16;
    const int nm1 = n - 1;
    const float4* Wv = (const float4*)W;
    const float* xr[16];
#pragma unroll
    for (int j = 0; j < 16; ++j) {
        int r = row0 + j;
        xr[j] = x + (size_t)(r > nm1 ? nm1 : r) * IN_CH;
    }
    v2f acc[16][2];
#pragma unroll
    for (int j = 0; j < 16; ++j) {
        acc[j][0] = (v2f){0.f, 0.f};
        acc[j][1] = (v2f){0.f, 0.f};
    }
    for (int k = 0; k < IN_CH; k += 4) {
        const float4 w0 = Wv[(k + 0) * 64 + c4];
        const float4 w1 = Wv[(k + 1) * 64 + c4];
        const float4 w2 = Wv[(k + 2) * 64 + c4];
        const float4 w3 = Wv[(k + 3) * 64 + c4];
        const v2f w0a = {w0.x, w0.y}, w0b = {w0.z, w0.w};
        const v2f w1a = {w1.x, w1.y}, w1b = {w1.z, w1.w};
        const v2f w2a = {w2.x, w2.y}, w2b = {w2.z, w2.w};
        const v2f w3a = {w3.x, w3.y}, w3b = {w3.z, w3.w};
#pragma unroll
        for (int jb = 0; jb < 2; ++jb) {
            float4 xv[8];
#pragma unroll
            for (int j = 0; j < 8; ++j) xv[j] = *(const float4*)(xr[jb * 8 + j] + k);
#pragma unroll
            for (int j = 0; j < 8; ++j) {
                const int a = jb * 8 + j;
                const v2f s0 = {xv[j].x, xv[j].x}, s1 = {xv[j].y, xv[j].y};
                const v2f s2 = {xv[j].z, xv[j].z}, s3 = {xv[j].w, xv[j].w};
                acc[a][0] = s0 * w0a + acc[a][0];
                acc[a][1] = s0 * w0b + acc[a][1];
                acc[a][0] = s1 * w1a + acc[a][0];
                acc[a][1] = s1 * w1b + acc[a][1];
                acc[a][0] = s2 * w2a + acc[a][0];
                acc[a][1] = s2 * w2b + acc[a][1];
                acc[a][0] = s3 * w3a + acc[a][0];
                acc[a][1] = s3 * w3b + acc[a][1];
            }
        }
    }
#pragma unroll
    for (int j = 0; j < 16; ++j) {
        const int row = row0 + j;
        if (row < n) {
            if (outh) {
                ushort4 h;
                h.x = f2bf_rne(acc[j][0].x);
                h.y = f2bf_rne(acc[j][0].y);
                h.z = f2bf_rne(acc[j][1].x);
                h.w = f2bf_rne(acc[j][1].y);
                ((ushort4*)(outh + (size_t)row * HC))[c4] = h;
            } else {
                *(float4*)(outf + (size_t)row * HC + 4 * c4) =
                    make_float4(acc[j][0].x, acc[j][0].y, acc[j][1].x, acc[j][1].y);
            }
        }
    }
}

__device__ __forceinline__ void dev_scatter_rank(const int* __restrict__ src1,
                                                 const int* __restrict__ dst1, int E1,
                                                 const int* __restrict__ src2,
                                                 const int* __restrict__ dst2, int E2,
                                                 int n, const int* __restrict__ offs,
                                                 const int* __restrict__ rank,
                                                 int* __restrict__ csr,
                                                 int bid, int nB) {
    const int Et = E1 + E2;
    for (int i = bid * 256 + threadIdx.x; i < Et; i += nB * 256) {
        if (i < E1) {
            csr[offs[ntldi(dst1 + i)] + ntldi(rank + i)] = ntldi(src1 + i) << 9;
        } else {
            int j = i - E1;
            csr[offs[n + ntldi(dst2 + j)] + ntldi(rank + i)] = ntldi(src2 + j) << 9;
        }
    }
}

__device__ __forceinline__ void dev_agg(const ushort_t* __restrict__ xlh,
                                        const float* __restrict__ xr,
                                        const float* __restrict__ att,
                                        const int* __restrict__ offs,
                                        const int* __restrict__ deg,
                                        const int* __restrict__ csr_src,
                                        int n, float* __restrict__ out,
                                        int selfLoop,
                                        const float* __restrict__ theta,
                                        int accumulate, int bid) {
    const int lane = threadIdx.x & 63;
    const int node = bid * 4 + (threadIdx.x >> 6);
    if (node >= n) return;

    const float4 attv = ((const float4*)att)[lane];
    const v2f a2a = {0.2f * attv.x, 0.2f * attv.y}, a2b = {0.2f * attv.z, 0.2f * attv.w};
    const v2f a8a = {0.8f * attv.x, 0.8f * attv.y}, a8b = {0.8f * attv.z, 0.8f * attv.w};
    const float4 q = ntld4(xr + (size_t)node * HC + 4 * lane);
    const v2f xa = {q.x, q.y}, xb = {q.z, q.w};
    const int start2 = offs[node] - selfLoop;
    const int total  = deg[node] + selfLoop;

    float l = 0.f;
    v2f Oa = {0.f, 0.f}, Ob = {0.f, 0.f};
    const char* Xc = (const char*)xlh;
    const unsigned laneB = (unsigned)lane * 8u;

    auto ld = [&](int i) -> uint2 {
        int off = (selfLoop && i == 0) ? (node << 9) : ntldi(csr_src + start2 + i);
        return *(const uint2*)(Xc + (unsigned)off + laneB);
    };
    auto process = [&](uint2 w) {
        v2f ca = bfpair(w.x), cb = bfpair(w.y);
        v2f za = ca + xa, zb = cb + xb;
        v2f t = a2a * za + a2b * zb + a8a * vmax0(za) + a8b * vmax0(zb);
        float part = rowsum16(t.x + t.y);
        float p = __expf(fminf(part, 60.f));
        l += p;
        v2f pp = {p, p};
        Oa = pp * ca + Oa;
        Ob = pp * cb + Ob;
    };

    if (total > 0) {
        uint2 b0 = ld(0);
        uint2 b1 = ld(1);
        uint2 b2 = ld(2);
        uint2 b3 = ld(3);
        int i = 0;
        for (; i + 4 <= total; i += 4) {
            uint2 c0 = b0, c1 = b1, c2 = b2, c3 = b3;
            b0 = ld(i + 4);
            b1 = ld(i + 5);
            b2 = ld(i + 6);
            b3 = ld(i + 7);
            process(c0);
            process(c1);
            process(c2);
            process(c3);
        }
        const int rem = total - i;
        if (rem > 0) process(b0);
        if (rem > 1) process(b1);
        if (rem > 2) process(b2);
    }

    float inv = (l > 0.f) ? 0.25f / l : 0.f;
    float vx = Oa.x * inv, vy = Oa.y * inv, vz = Ob.x * inv, vw = Ob.y * inv;
    vx += __shfl_xor(vx, 16); vx += __shfl_xor(vx, 32);
    vy += __shfl_xor(vy, 16); vy += __shfl_xor(vy, 32);
    vz += __shfl_xor(vz, 16); vz += __shfl_xor(vz, 32);
    vw += __shfl_xor(vw, 16); vw += __shfl_xor(vw, 32);

    if (lane < 16) {
        float4 r = make_float4(vx, vy, vz, vw);
        float4* op = (float4*)(out + (size_t)node * OUT_C);
        if (accumulate) {
            float sg = 1.f / (1.f + __expf(-theta[0]));
            float4 cur = op[lane];
            r.x = fmaf(sg, r.x, cur.x);
            r.y = fmaf(sg, r.y, cur.y);
            r.z = fmaf(sg, r.z, cur.z);
            r.w = fmaf(sg, r.w, cur.w);
        }
        op[lane] = r;
    }
}

__global__ __launch_bounds__(256) void k_mix1(const float* __restrict__ x,
                                              const float* __restrict__ Wa,
                                              ushort_t* __restrict__ oah,
                                              const float* __restrict__ Wb,
                                              float* __restrict__ ob, int n,
                                              int GH, int gG,
                                              const int* __restrict__ dst1, int E1,
                                              const int* __restrict__ dst2, int E2,
                                              int* __restrict__ deg,
                                              int* __restrict__ rank) {
    const int bx = blockIdx.x;
    if (bx < GH) {
        const int Et = E1 + E2;
        for (int i = bx * 256 + threadIdx.x; i < Et; i += GH * 256) {
            if (i < E1) rank[i] = atomicAdd(&deg[dst1[i]], 1);
            else        rank[i] = atomicAdd(&deg[n + dst2[i - E1]], 1);
        }
    } else {
        int t = bx - GH;
        if (t < gG) dev_gemm(x, Wa, nullptr, oah, n, t);
        else        dev_gemm(x, Wb, ob, nullptr, n, t - gG);
    }
}

__global__ __launch_bounds__(256) void k_mix2(const float* __restrict__ x,
                                              const float* __restrict__ Wc,
                                              float* __restrict__ oc, int n,
                                              int GS,
                                              const int* __restrict__ src1,
                                              const int* __restrict__ dst1, int E1,
                                              const int* __restrict__ src2,
                                              const int* __restrict__ dst2, int E2,
                                              const int* __restrict__ offs,
                                              const int* __restrict__ rank,
                                              int* __restrict__ csr) {
    const int bx = blockIdx.x;
    if (bx < GS)
        dev_scatter_rank(src1, dst1, E1, src2, dst2, E2, n, offs, rank, csr, bx, GS);
    else
        dev_gemm(x, Wc, oc, nullptr, n, bx - GS);
}

__global__ __launch_bounds__(256) void k_mix3(const ushort_t* __restrict__ xlh,
                                              const float* __restrict__ xr,
                                              const float* __restrict__ att,
                                              const int* __restrict__ offs,
                                              const int* __restrict__ deg,
                                              const int* __restrict__ csr_src,
                                              int n, float* __restrict__ out,
                                              int selfLoop,
                                              const float* __restrict__ theta,
                                              int accumulate) {
    dev_agg(xlh, xr, att, offs, deg, csr_src, n, out, selfLoop, theta,
            accumulate, blockIdx.x);
}

__global__ __launch_bounds__(1024) void k_scanA(const int* __restrict__ deg, int n,
                                                int* __restrict__ incl,
                                                int* __restrict__ bsum) {
    __shared__ int sm[1024];
    const int t = threadIdx.x;
    const int i = blockIdx.x * 1024 + t;
    sm[t] = (i < n) ? deg[i] : 0;
    for (int off = 1; off < 1024; off <<= 1) {
        __syncthreads();
        int u = (t >= off) ? sm[t - off] : 0;
        __syncthreads();
        sm[t] += u;
    }
    if (i < n) incl[i] = sm[t];
    if (t == 1023) bsum[blockIdx.x] = sm[1023];
}

__global__ __launch_bounds__(1024) void k_scanB(int* __restrict__ bsum, int nb) {
    __shared__ int sm[1024];
    const int t = threadIdx.x;
    sm[t] = (t < nb) ? bsum[t] : 0;
    for (int off = 1; off < 1024; off <<= 1) {
        __syncthreads();
        int u = (t >= off) ? sm[t - off] : 0;
        __syncthreads();
        sm[t] += u;
    }
    if (t < nb) bsum[t] = sm[t];
}

__global__ void k_scanCf(const int* __restrict__ incl, const int* __restrict__ deg,
                         const int* __restrict__ bsum, int nb, int n,
                         int* __restrict__ offs) {
    __shared__ int sb[128];
    const int t = threadIdx.x;
    if (t < 128) sb[t] = (t < nb) ? bsum[t] : 0;
    __syncthreads();
#pragma unroll
    for (int off = 1; off < 128; off <<= 1) {
        int u = (t >= off && t < 128) ? sb[t - off] : 0;
        __syncthreads();
        if (t < 128) sb[t] += u;
        __syncthreads();
    }
    int i = blockIdx.x * 256 + t;
    if (i < n) {
        int b    = i >> 10;
        int base = (b > 0) ? sb[b - 1] : 0;
        offs[i] = base + incl[i] - deg[i];
    }
}

__global__ void k_scanC(const int* __restrict__ incl, const int* __restrict__ deg,
                        const int* __restrict__ bsum, int n,
                        int* __restrict__ offs) {
    int i = blockIdx.x * 256 + threadIdx.x;
    if (i < n) {
        int b    = i >> 10;
        int base = (b > 0) ? bsum[b - 1] : 0;
        offs[i] = base + incl[i] - deg[i];
    }
}

// ---------------------------------------------------------------------------
extern "C" void kernel_launch(void* const* d_in, const int* in_sizes, int n_in,
                              void* d_out, int out_size, void* d_ws, size_t ws_size,
                              hipStream_t stream) {
    const float* x     = (const float*)d_in[0];
    const int*   e1    = (const int*)d_in[1];
    const int*   e2    = (const int*)d_in[2];
    const float* Wl    = (const float*)d_in[3];
    const float* Wr0   = (const float*)d_in[4];
    const float* Wr1   = (const float*)d_in[5];
    const float* att0  = (const float*)d_in[6];
    const float* att1  = (const float*)d_in[7];
    const float* theta = (const float*)d_in[8];

    const int n  = in_sizes[0] / IN_CH;  // 50000
    const int E1 = in_sizes[1] / 2;
    const int E2 = in_sizes[2] / 2;
    float* out = (float*)d_out;

    char* w = (char*)d_ws;
    auto alloc = [&](size_t bytes) -> char* {
        char* p = w;
        w += (bytes + 255) & ~(size_t)255;
        return p;
    };
    auto al = [](size_t b) -> size_t { return (b + 255) & ~(size_t)255; };

    const int gT = (n + 63) / 64;              // 64-row GEMM tiles
    const size_t projH = (size_t)n * HC * 2;   // bf16 xl
    const size_t projF = (size_t)n * HC * 4;   // f32 xr
    const size_t degB  = (size_t)2 * n * 4;
    const size_t csrS  = (size_t)2 * n * CSTR * 4;      // fixed-stride csr
    const size_t xAB   = (size_t)gT * 1024 * 16;        // packed A frags (uint4)
    const size_t WBB   = (size_t)3 * 4 * 16 * 64 * 16;  // packed B frags

    const size_t needMS = al(projH) + 2 * al(projF) + al(csrS) + al(degB)
                        + 2 * al(xAB) + 2 * al(WBB) + 4096;

    const int GH  = 2048;
    const int n2  = 2 * n;

    if (ws_size >= needMS) {
        // ---------- fast path: fused hist+scatter, MFMA gemm, fused agg ----
        ushort_t* xlh = (ushort_t*)alloc(projH);
        float* xr0 = (float*)alloc(projF);
        float* xr1 = (float*)alloc(projF);
        int* csr   = (int*)alloc(csrS);
        int* deg   = (int*)alloc(degB);
        uint4* xAh = (uint4*)alloc(xAB);
        uint4* xAl = (uint4*)alloc(xAB);
        uint4* WBh = (uint4*)alloc(WBB);
        uint4* WBl = (uint4*)alloc(WBB);
        const int gPX = gT * 4;          // x-pack blocks (exact)
        const int gPW = 48;              // W-pack blocks (exact: 12288/256)

        hipMemsetAsync(deg, 0, degB, stream);
        // fused hist+scatter (both hops) || x-split-pack || W-split-pack
        k_hs<<<GH + gPX + gPW, 256, 0, stream>>>(x, Wl, Wr0, Wr1,
                                                 xAh, xAl, WBh, WBl,
                                                 n, GH, gPX,
                                                 e1, e1 + E1, E1,
                                                 e2, e2 + E2, E2,
                                                 deg, csr);
        // pure MFMA gemm x3 (XCD-congruent tile grouping)
        k_gemm3<<<3 * gT, 256, 0, stream>>>(xAh, xAl, WBh, WBl,
                                            xlh, xr0, xr1, n, gT);
        // fused both-hop aggregation: 2 nodes per 128-thread block
        k_aggboth<<<(n + 1) / 2, 128, 0, stream>>>(xlh, xr0, xr1, att0, att1,
                                                   deg, csr, n, out, theta);
        return;
    }

    // ---------- fallback: old scan-based VALU path ----------
    const size_t eB = (size_t)(E1 + E2) * 4 + 256;
    ushort_t* xlh = (ushort_t*)alloc(projH);
    float* xr0 = (float*)alloc(projF);
    float* xr1 = xr0;
    int* csr  = (int*)alloc(eB);
    int* rank = (int*)alloc(eB);
    int* deg  = (int*)alloc(degB);
    int* offs = (int*)alloc(degB);
    int* tmp  = (int*)alloc(degB);
    int* bsum = (int*)alloc(4096);

    const int gG  = gT;
    const int GS  = 2048;
    const int GA4 = (n + 3) / 4;
    const int gN2   = (n2 + 255) / 256;
    const int nScan = (n2 + 1023) / 1024;

    hipMemsetAsync(deg, 0, degB, stream);
    hipMemsetAsync(csr + E1 + E2, 0, 256, stream);
    k_mix1<<<GH + 2 * gG, 256, 0, stream>>>(x, Wl, xlh, Wr0, xr0, n, GH, gG,
                                            e1 + E1, E1, e2 + E2, E2, deg, rank);
    k_scanA<<<nScan, 1024, 0, stream>>>(deg, n2, tmp, bsum);
    if (nScan <= 128) {
        k_scanCf<<<gN2, 256, 0, stream>>>(tmp, deg, bsum, nScan, n2, offs);
    } else {
        k_scanB<<<1, 1024, 0, stream>>>(bsum, nScan);
        k_scanC<<<gN2, 256, 0, stream>>>(tmp, deg, bsum, n2, offs);
    }
    k_mix2<<<GS, 256, 0, stream>>>(x, Wr1, xr1, n, GS,
                                   e1, e1 + E1, E1, e2, e2 + E2, E2,
                                   offs, rank, csr);
    k_mix3<<<GA4, 256, 0, stream>>>(xlh, xr0, att0, offs, deg, csr, n, out,
                                    1, theta, 0);
    k_mix2<<<gG, 256, 0, stream>>>(x, Wr1, xr0, n, 0,
                                   (const int*)nullptr, (const int*)nullptr, 0,
                                   (const int*)nullptr, (const int*)nullptr, 0,
                                   (const int*)nullptr, (const int*)nullptr,
                                   (int*)nullptr);
    k_mix3<<<GA4, 256, 0, stream>>>(xlh, xr0, att1, offs + n, deg + n, csr, n, out,
                                    0, theta, 1);
}

// Round 10
// 347.453 us; speedup vs baseline: 1.0980x; 1.0980x over previous
//
#include <hip/hip_runtime.h>
#include <hip/hip_bf16.h>
#include <math.h>

#define IN_CH   128
#define HC      256   // HEADS*OUT_C
#define OUT_C   64

typedef unsigned short ushort_t;
typedef __attribute__((ext_vector_type(2))) float v2f;
typedef __attribute__((ext_vector_type(4))) float v4f;
typedef __attribute__((ext_vector_type(8))) short bf16x8;   // 8 bf16 (4 VGPRs)

__device__ __forceinline__ ushort_t f2bf_rne(float f) {
    unsigned u = __float_as_uint(f);
    unsigned r = (u + 0x7FFFu + ((u >> 16) & 1u)) >> 16;
    return (ushort_t)r;
}
__device__ __forceinline__ v2f bfpair(unsigned u) {
    v2f r;
    r.x = __uint_as_float(u << 16);
    r.y = __uint_as_float(u & 0xffff0000u);
    return r;
}
__device__ __forceinline__ v2f vmax0(v2f a) {
    v2f r;
    r.x = fmaxf(a.x, 0.f);
    r.y = fmaxf(a.y, 0.f);
    return r;
}

// ---- nontemporal helpers: ONLY for data not re-read by a later kernel ----
__device__ __forceinline__ float4 ntld4(const float* p) {
    v4f t = __builtin_nontemporal_load((const v4f*)p);
    return make_float4(t.x, t.y, t.z, t.w);
}
__device__ __forceinline__ int ntldi(const int* p) {
    return __builtin_nontemporal_load(p);
}
__device__ __forceinline__ void ntst4(float* p, float4 v) {
    v4f t = {v.x, v.y, v.z, v.w};
    __builtin_nontemporal_store(t, (v4f*)p);
}

// ---- 16-lane (DPP-row) sum via row_ror rotations: pure VALU, no LDS pipe.
#define DPP_ROR_ADD(x, N)                                                   \
    (x) += __uint_as_float(__builtin_amdgcn_update_dpp(                     \
        0, __float_as_uint(x), 0x120 + (N), 0xF, 0xF, true))

__device__ __forceinline__ float rowsum16(float x) {
    DPP_ROR_ADD(x, 8);
    DPP_ROR_ADD(x, 4);
    DPP_ROR_ADD(x, 2);
    DPP_ROR_ADD(x, 1);
    return x;
}

__device__ __forceinline__ bf16x8 ldbf(const uint4* p) {
    union { uint4 u; bf16x8 v; } t;
    t.u = *p;
    return t.v;
}

// ===========================================================================
// OLD VALU GEMM (workspace-fallback path only).
// ===========================================================================
__device__ __forceinline__ void dev_gemm(const float* __restrict__ x,
                                         const float* __restrict__ W,
                                         float* __restrict__ outf,
                                         ushort_t* __restrict__ outh,
                                         int n, int bx) {
    const int tid = threadIdx.x;
    const int c4  = tid & 63;
    const int rg  = __builtin_amdgcn_readfirstlane(tid >> 6);
    const int row0 = bx * 64 + rg * 16;
    const int nm1 = n - 1;
    const float4* Wv = (const float4*)W;
    const float* xr[16];
#pragma unroll
    for (int j = 0; j < 16; ++j) {
        int r = row0 + j;
        xr[j] = x + (size_t)(r > nm1 ? nm1 : r) * IN_CH;
    }
    v2f acc[16][2];
#pragma unroll
    for (int j = 0; j < 16; ++j) {
        acc[j][0] = (v2f){0.f, 0.f};
        acc[j][1] = (v2f){0.f, 0.f};
    }
    for (int k = 0; k < IN_CH; k += 4) {
        const float4 w0 = Wv[(k + 0) * 64 + c4];
        const float4 w1 = Wv[(k + 1) * 64 + c4];
        const float4 w2 = Wv[(k + 2) * 64 + c4];
        const float4 w3 = Wv[(k + 3) * 64 + c4];
        const v2f w0a = {w0.x, w0.y}, w0b = {w0.z, w0.w};
        const v2f w1a = {w1.x, w1.y}, w1b = {w1.z, w1.w};
        const v2f w2a = {w2.x, w2.y}, w2b = {w2.z, w2.w};
        const v2f w3a = {w3.x, w3.y}, w3b = {w3.z, w3.w};
#pragma unroll
        for (int jb = 0; jb < 2; ++jb) {
            float4 xv[8];
#pragma unroll
            for (int j = 0; j < 8; ++j) xv[j] = *(const float4*)(xr[jb * 8 + j] + k);
#pragma unroll
            for (int j = 0; j < 8; ++j) {
                const int a = jb * 8 + j;
                const v2f s0 = {xv[j].x, xv[j].x}, s1 = {xv[j].y, xv[j].y};
                const v2f s2 = {xv[j].z, xv[j].z}, s3 = {xv[j].w, xv[j].w};
                acc[a][0] = s0 * w0a + acc[a][0];
                acc[a][1] = s0 * w0b + acc[a][1];
                acc[a][0] = s1 * w1a + acc[a][0];
                acc[a][1] = s1 * w1b + acc[a][1];
                acc[a][0] = s2 * w2a + acc[a][0];
                acc[a][1] = s2 * w2b + acc[a][1];
                acc[a][0] = s3 * w3a + acc[a][0];
                acc[a][1] = s3 * w3b + acc[a][1];
            }
        }
    }
#pragma unroll
    for (int j = 0; j < 16; ++j) {
        const int row = row0 + j;
        if (row < n) {
            if (outh) {
                ushort4 h;
                h.x = f2bf_rne(acc[j][0].x);
                h.y = f2bf_rne(acc[j][0].y);
                h.z = f2bf_rne(acc[j][1].x);
                h.w = f2bf_rne(acc[j][1].y);
                ((ushort4*)(outh + (size_t)row * HC))[c4] = h;
            } else {
                *(float4*)(outf + (size_t)row * HC + 4 * c4) =
                    make_float4(acc[j][0].x, acc[j][0].y, acc[j][1].x, acc[j][1].y);
            }
        }
    }
}

// Atomic-free scatter; csr stores BYTE offsets (src*512). csr stores CACHED
// (compact layout: a node's ~16 entries fill one 64B line -> L2 absorbs);
// src/dst/rank reads NT (dead after this pass).
__device__ __forceinline__ void dev_scatter_rank(const int* __restrict__ src1,
                                                 const int* __restrict__ dst1, int E1,
                                                 const int* __restrict__ src2,
                                                 const int* __restrict__ dst2, int E2,
                                                 int n, const int* __restrict__ offs,
                                                 const int* __restrict__ rank,
                                                 int* __restrict__ csr,
                                                 int bid, int nB) {
    const int Et = E1 + E2;
    for (int i = bid * 256 + threadIdx.x; i < Et; i += nB * 256) {
        if (i < E1) {
            csr[offs[ntldi(dst1 + i)] + ntldi(rank + i)] = ntldi(src1 + i) << 9;
        } else {
            int j = i - E1;
            csr[offs[n + ntldi(dst2 + j)] + ntldi(rank + i)] = ntldi(src2 + j) << 9;
        }
    }
}

// ===========================================================================
// HP: mixed grid — hist+rank (latency-bound atomics) || x/W split-pack
// (memory-bound). Block roles are INTERLEAVED (groups of 5 = 2 hist +
// 3 pack) so both phases are co-resident from dispatch 0 and the atomic
// latency hides under the pack streaming (R7 put all hist blocks first,
// which serialized the phases at the dispatcher). hist block 0 also zeros
// the csr tail pad (replaces a memset launch).
// ===========================================================================
__global__ __launch_bounds__(256) void k_hp(const float* __restrict__ x,
                                            const float* __restrict__ Wl,
                                            const float* __restrict__ Wr0,
                                            const float* __restrict__ Wr1,
                                            uint4* __restrict__ xAh,
                                            uint4* __restrict__ xAl,
                                            uint4* __restrict__ WBh,
                                            uint4* __restrict__ WBl,
                                            int n, int GH, int gP, int gPX,
                                            const int* __restrict__ dst1, int E1,
                                            const int* __restrict__ dst2, int E2,
                                            int* __restrict__ deg,
                                            int* __restrict__ rank,
                                            int* __restrict__ csrpad) {
    const int bx = blockIdx.x;
    // role interleave: grp groups of (2 hist + 3 pack), then tails
    const int grp = min(GH >> 1, gP / 3);
    const int cov = grp * 5;
    const int histRem = GH - 2 * grp;
    int hist_id = -1, pack_id = -1;
    if (bx < cov) {
        const int g = bx / 5, r = bx - g * 5;
        if (r < 2) hist_id = g * 2 + r;
        else       pack_id = g * 3 + (r - 2);
    } else if (bx < cov + histRem) {
        hist_id = 2 * grp + (bx - cov);
    } else {
        pack_id = 3 * grp + (bx - cov - histRem);
    }

    if (hist_id >= 0) {
        if (hist_id == 0 && threadIdx.x < 64) csrpad[threadIdx.x] = 0;
        const int Et = E1 + E2;
        for (int i = hist_id * 256 + threadIdx.x; i < Et; i += GH * 256) {
            if (i < E1) rank[i] = atomicAdd(&deg[dst1[i]], 1);
            else        rank[i] = atomicAdd(&deg[n + dst2[i - E1]], 1);
        }
        return;
    }

    const int t = pack_id;
    float v[8];
    ushort_t h[8], l[8];
    if (t < gPX) {
        const int di  = t * 256 + threadIdx.x;        // sequential store index
        const int row = ((di >> 8) << 4) | (di & 15);
        const int ko  = ((di >> 4) & 3) | (((di >> 6) & 3) << 2);
        float4 v0 = make_float4(0.f, 0.f, 0.f, 0.f), v1 = v0;
        if (row < n) {
            const float4* xp = (const float4*)(x + (size_t)row * IN_CH + ko * 8);
            v0 = xp[0];
            v1 = xp[1];
        }
        v[0] = v0.x; v[1] = v0.y; v[2] = v0.z; v[3] = v0.w;
        v[4] = v1.x; v[5] = v1.y; v[6] = v1.z; v[7] = v1.w;
#pragma unroll
        for (int j = 0; j < 8; ++j) {
            h[j] = f2bf_rne(v[j]);
            l[j] = f2bf_rne(v[j] - __uint_as_float((unsigned)h[j] << 16));
        }
        uint4 ph, pl;
        ph.x = (unsigned)h[0] | ((unsigned)h[1] << 16);
        ph.y = (unsigned)h[2] | ((unsigned)h[3] << 16);
        ph.z = (unsigned)h[4] | ((unsigned)h[5] << 16);
        ph.w = (unsigned)h[6] | ((unsigned)h[7] << 16);
        pl.x = (unsigned)l[0] | ((unsigned)l[1] << 16);
        pl.y = (unsigned)l[2] | ((unsigned)l[3] << 16);
        pl.z = (unsigned)l[4] | ((unsigned)l[5] << 16);
        pl.w = (unsigned)l[6] | ((unsigned)l[7] << 16);
        xAh[di] = ph;
        xAl[di] = pl;
    } else {
        const int idx = (t - gPX) * 256 + threadIdx.x;   // [0, 3*4*16*64)
        const int lane = idx & 63;
        const int f    = (idx >> 6) & 15;
        const int c    = (idx >> 10) & 3;
        const int w    = idx >> 12;
        if (w >= 3) return;
        const float* Wp = (w == 0) ? Wl : ((w == 1) ? Wr0 : Wr1);
        const int col = f * 16 + (lane & 15);
        const int k0  = c * 32 + (lane >> 4) * 8;
#pragma unroll
        for (int j = 0; j < 8; ++j) {
            v[j] = Wp[(size_t)(k0 + j) * HC + col];
            h[j] = f2bf_rne(v[j]);
            l[j] = f2bf_rne(v[j] - __uint_as_float((unsigned)h[j] << 16));
        }
        uint4 ph, pl;
        ph.x = (unsigned)h[0] | ((unsigned)h[1] << 16);
        ph.y = (unsigned)h[2] | ((unsigned)h[3] << 16);
        ph.z = (unsigned)h[4] | ((unsigned)h[5] << 16);
        ph.w = (unsigned)h[6] | ((unsigned)h[7] << 16);
        pl.x = (unsigned)l[0] | ((unsigned)l[1] << 16);
        pl.y = (unsigned)l[2] | ((unsigned)l[3] << 16);
        pl.z = (unsigned)l[4] | ((unsigned)l[5] << 16);
        pl.w = (unsigned)l[6] | ((unsigned)l[7] << 16);
        WBh[idx] = ph;
        WBl[idx] = pl;
    }
}

// ===========================================================================
// MFMA GEMM x @ {Wl, Wr0, Wr1} (split-bf16, 3-term) + scatter mixed in.
// XCD-congruent tile mapping (3 wsel-blocks of a tile land on one XCD/L2).
// ===========================================================================
__global__ __launch_bounds__(256) void k_gemm3(const uint4* __restrict__ xAh,
                                               const uint4* __restrict__ xAl,
                                               const uint4* __restrict__ WBh,
                                               const uint4* __restrict__ WBl,
                                               ushort_t* __restrict__ xlh,
                                               float* __restrict__ xr0,
                                               float* __restrict__ xr1,
                                               int n, int GS, int gT,
                                               const int* __restrict__ src1,
                                               const int* __restrict__ dst1, int E1,
                                               const int* __restrict__ src2,
                                               const int* __restrict__ dst2, int E2,
                                               const int* __restrict__ offs,
                                               const int* __restrict__ rank,
                                               int* __restrict__ csr) {
    const int bx = blockIdx.x;
    if (bx < GS) {
        dev_scatter_rank(src1, dst1, E1, src2, dst2, E2, n, offs, rank, csr, bx, GS);
        return;
    }
    const int t = bx - GS;
    const int gT8 = (gT / 8) * 8;       // tiles covered by full 24-windows
    int tile, wsel;
    if (t < 3 * gT8) {
        const int k = t / 24;
        const int r = t - k * 24;
        tile = k * 8 + (r & 7);
        wsel = r >> 3;
    } else {
        const int u = t - 3 * gT8;
        tile = gT8 + u / 3;
        wsel = u - (u / 3) * 3;
    }

    const int lane = threadIdx.x & 63;
    const int wave = __builtin_amdgcn_readfirstlane((int)(threadIdx.x >> 6));

    v4f acc[4][4];
#pragma unroll
    for (int g = 0; g < 4; ++g)
#pragma unroll
        for (int f = 0; f < 4; ++f) acc[g][f] = (v4f){0.f, 0.f, 0.f, 0.f};

    const uint4* Bh = WBh + (size_t)wsel * 4096;
    const uint4* Bl = WBl + (size_t)wsel * 4096;
    const int g0 = tile * 4;

    for (int c = 0; c < 4; ++c) {
        bf16x8 ah[4], al[4], bh[4], bl[4];
#pragma unroll
        for (int g = 0; g < 4; ++g) {
            const int ai = ((g0 + g) * 4 + c) * 64 + lane;
            ah[g] = ldbf(xAh + ai);
            al[g] = ldbf(xAl + ai);
        }
#pragma unroll
        for (int f = 0; f < 4; ++f) {
            const int bi = (c * 16 + wave * 4 + f) * 64 + lane;
            bh[f] = ldbf(Bh + bi);
            bl[f] = ldbf(Bl + bi);
        }
#pragma unroll
        for (int g = 0; g < 4; ++g)
#pragma unroll
            for (int f = 0; f < 4; ++f) {
                acc[g][f] = __builtin_amdgcn_mfma_f32_16x16x32_bf16(ah[g], bh[f], acc[g][f], 0, 0, 0);
                acc[g][f] = __builtin_amdgcn_mfma_f32_16x16x32_bf16(ah[g], bl[f], acc[g][f], 0, 0, 0);
                acc[g][f] = __builtin_amdgcn_mfma_f32_16x16x32_bf16(al[g], bh[f], acc[g][f], 0, 0, 0);
            }
    }

    const int colB = wave * 64 + (lane & 15);
    const int rowB = tile * 64 + ((lane >> 4) << 2);
    if (wsel == 0) {
#pragma unroll
        for (int g = 0; g < 4; ++g)
#pragma unroll
            for (int f = 0; f < 4; ++f) {
                const int col = colB + f * 16;
#pragma unroll
                for (int r = 0; r < 4; ++r) {
                    const int row = rowB + g * 16 + r;
                    if (row < n) xlh[(size_t)row * HC + col] = f2bf_rne(acc[g][f][r]);
                }
            }
    } else {
        float* o = (wsel == 1) ? xr0 : xr1;
#pragma unroll
        for (int g = 0; g < 4; ++g)
#pragma unroll
            for (int f = 0; f < 4; ++f) {
                const int col = colB + f * 16;
#pragma unroll
                for (int r = 0; r < 4; ++r) {
                    const int row = rowB + g * 16 + r;
                    if (row < n) o[(size_t)row * HC + col] = acc[g][f][r];   // cached
                }
            }
    }
}

// ===========================================================================
// BOTH-HOP fused aggregation (R7 version — proven 123 us; R8's explicit
// double-buffer regressed). csr batches lane-spread + readlane -> SGPR-base
// gathers; both hops' first batches prefetched. Per-stream accumulation
// order unchanged.
// ===========================================================================
__global__ __launch_bounds__(128) void k_aggboth(const ushort_t* __restrict__ xlh,
                                                 const float* __restrict__ xr0,
                                                 const float* __restrict__ xr1,
                                                 const float* __restrict__ att0,
                                                 const float* __restrict__ att1,
                                                 const int* __restrict__ offs,
                                                 const int* __restrict__ deg,
                                                 const int* __restrict__ csr,
                                                 int n, float* __restrict__ out,
                                                 const float* __restrict__ theta) {
    const int lane = threadIdx.x & 63;
    int node_ = blockIdx.x * 2 + (threadIdx.x >> 6);
    if (node_ >= n) return;
    const int node = __builtin_amdgcn_readfirstlane(node_);

    const float th = theta[0];                       // hoisted scalar load

    const float4 at0 = ((const float4*)att0)[lane];
    const float4 at1 = ((const float4*)att1)[lane];
    const v2f a2_0a = {0.2f * at0.x, 0.2f * at0.y}, a2_0b = {0.2f * at0.z, 0.2f * at0.w};
    const v2f a8_0a = {0.8f * at0.x, 0.8f * at0.y}, a8_0b = {0.8f * at0.z, 0.8f * at0.w};
    const v2f a2_1a = {0.2f * at1.x, 0.2f * at1.y}, a2_1b = {0.2f * at1.z, 0.2f * at1.w};
    const v2f a8_1a = {0.8f * at1.x, 0.8f * at1.y}, a8_1b = {0.8f * at1.z, 0.8f * at1.w};
    const float4 q0 = ntld4(xr0 + (size_t)node * HC + 4 * lane);
    const float4 q1 = ntld4(xr1 + (size_t)node * HC + 4 * lane);
    const v2f x0a = {q0.x, q0.y}, x0b = {q0.z, q0.w};
    const v2f x1a = {q1.x, q1.y}, x1b = {q1.z, q1.w};

    const int t0 = deg[node];
    const int s0 = offs[node];
    const int t1 = deg[n + node];
    const int s1 = offs[n + node];

    const char* Xc = (const char*)xlh;
    const unsigned laneB = (unsigned)lane * 8u;
    auto gath = [&](unsigned off) -> uint2 {        // off is wave-uniform (SGPR)
        const char* p = Xc + off;                   // s_add -> SGPR base
        return *(const uint2*)(p + laneB);          // s-base + v-offset load
    };

    float l0 = 0.f, l1 = 0.f;
    v2f O0a = {0.f, 0.f}, O0b = {0.f, 0.f};
    v2f O1a = {0.f, 0.f}, O1b = {0.f, 0.f};

    auto proc = [&](uint2 w, const v2f& xa, const v2f& xb,
                    const v2f& a8a, const v2f& a8b,
                    const v2f& a2a, const v2f& a2b, float& l, v2f& Oa, v2f& Ob) {
        v2f ca = bfpair(w.x), cb = bfpair(w.y);
        v2f za = ca + xa, zb = cb + xb;
        v2f t = a2a * za + a2b * zb + a8a * vmax0(za) + a8b * vmax0(zb);
        float part = rowsum16(t.x + t.y);
        float p = __expf(fminf(part, 60.f));
        l += p;
        v2f pp = {p, p};
        Oa = pp * ca + Oa;
        Ob = pp * cb + Ob;
    };
    auto proc0 = [&](uint2 w) { proc(w, x0a, x0b, a8_0a, a8_0b, a2_0a, a2_0b, l0, O0a, O0b); };
    auto proc1 = [&](uint2 w) { proc(w, x1a, x1b, a8_1a, a8_1b, a2_1a, a2_1b, l1, O1a, O1b); };

    // Prefetch BOTH hops' first csr batches; latency hides under self-loop.
    unsigned vc0p = 0, vc1p = 0;
    if (t0 > 0) vc0p = (unsigned)csr[s0 + lane];
    if (t1 > 0) vc1p = (unsigned)csr[s1 + lane];

    proc0(gath((unsigned)node << 9));               // virtual self loop

    // ---- hop 0 ----
    for (int base = 0; base < t0; base += 64) {
        const unsigned vc = (base == 0) ? vc0p : (unsigned)csr[s0 + base + lane];
        const int m = (t0 - base < 64) ? (t0 - base) : 64;
        int j = 0;
        for (; j + 8 <= m; j += 8) {
            uint2 g0 = gath((unsigned)__builtin_amdgcn_readlane(vc, j + 0));
            uint2 g1 = gath((unsigned)__builtin_amdgcn_readlane(vc, j + 1));
            uint2 g2 = gath((unsigned)__builtin_amdgcn_readlane(vc, j + 2));
            uint2 g3 = gath((unsigned)__builtin_amdgcn_readlane(vc, j + 3));
            uint2 g4 = gath((unsigned)__builtin_amdgcn_readlane(vc, j + 4));
            uint2 g5 = gath((unsigned)__builtin_amdgcn_readlane(vc, j + 5));
            uint2 g6 = gath((unsigned)__builtin_amdgcn_readlane(vc, j + 6));
            uint2 g7 = gath((unsigned)__builtin_amdgcn_readlane(vc, j + 7));
            proc0(g0); proc0(g1); proc0(g2); proc0(g3);
            proc0(g4); proc0(g5); proc0(g6); proc0(g7);
        }
        for (; j + 2 <= m; j += 2) {
            uint2 g0 = gath((unsigned)__builtin_amdgcn_readlane(vc, j + 0));
            uint2 g1 = gath((unsigned)__builtin_amdgcn_readlane(vc, j + 1));
            proc0(g0); proc0(g1);
        }
        if (j < m) proc0(gath((unsigned)__builtin_amdgcn_readlane(vc, j)));
    }

    // ---- hop 1 ----
    for (int base = 0; base < t1; base += 64) {
        const unsigned vc = (base == 0) ? vc1p : (unsigned)csr[s1 + base + lane];
        const int m = (t1 - base < 64) ? (t1 - base) : 64;
        int j = 0;
        for (; j + 8 <= m; j += 8) {
            uint2 g0 = gath((unsigned)__builtin_amdgcn_readlane(vc, j + 0));
            uint2 g1 = gath((unsigned)__builtin_amdgcn_readlane(vc, j + 1));
            uint2 g2 = gath((unsigned)__builtin_amdgcn_readlane(vc, j + 2));
            uint2 g3 = gath((unsigned)__builtin_amdgcn_readlane(vc, j + 3));
            uint2 g4 = gath((unsigned)__builtin_amdgcn_readlane(vc, j + 4));
            uint2 g5 = gath((unsigned)__builtin_amdgcn_readlane(vc, j + 5));
            uint2 g6 = gath((unsigned)__builtin_amdgcn_readlane(vc, j + 6));
            uint2 g7 = gath((unsigned)__builtin_amdgcn_readlane(vc, j + 7));
            proc1(g0); proc1(g1); proc1(g2); proc1(g3);
            proc1(g4); proc1(g5); proc1(g6); proc1(g7);
        }
        for (; j + 2 <= m; j += 2) {
            uint2 g0 = gath((unsigned)__builtin_amdgcn_readlane(vc, j + 0));
            uint2 g1 = gath((unsigned)__builtin_amdgcn_readlane(vc, j + 1));
            proc1(g0); proc1(g1);
        }
        if (j < m) proc1(gath((unsigned)__builtin_amdgcn_readlane(vc, j)));
    }

    const float inv0 = 0.25f / l0;
    const float inv1 = (l1 > 0.f) ? 0.25f / l1 : 0.f;
    const float sg = 1.f / (1.f + __expf(-th));
    float vx = O0a.x * inv0 + sg * (O1a.x * inv1);
    float vy = O0a.y * inv0 + sg * (O1a.y * inv1);
    float vz = O0b.x * inv0 + sg * (O1b.x * inv1);
    float vw = O0b.y * inv0 + sg * (O1b.y * inv1);
    vx += __shfl_xor(vx, 16); vx += __shfl_xor(vx, 32);
    vy += __shfl_xor(vy, 16); vy += __shfl_xor(vy, 32);
    vz += __shfl_xor(vz, 16); vz += __shfl_xor(vz, 32);
    vw += __shfl_xor(vw, 16); vw += __shfl_xor(vw, 32);

    if (lane < 16) {
        ntst4(out + (size_t)node * OUT_C + 4 * lane, make_float4(vx, vy, vz, vw));
    }
}

// ===========================================================================
// Single-hop aggregation (fallback path).
// ===========================================================================
__device__ __forceinline__ void dev_agg(const ushort_t* __restrict__ xlh,
                                        const float* __restrict__ xr,
                                        const float* __restrict__ att,
                                        const int* __restrict__ offs,
                                        const int* __restrict__ deg,
                                        const int* __restrict__ csr_src,
                                        int n, float* __restrict__ out,
                                        int selfLoop,
                                        const float* __restrict__ theta,
                                        int accumulate, int bid) {
    const int lane = threadIdx.x & 63;
    const int node = bid * 4 + (threadIdx.x >> 6);
    if (node >= n) return;

    const float4 attv = ((const float4*)att)[lane];
    const v2f a2a = {0.2f * attv.x, 0.2f * attv.y}, a2b = {0.2f * attv.z, 0.2f * attv.w};
    const v2f a8a = {0.8f * attv.x, 0.8f * attv.y}, a8b = {0.8f * attv.z, 0.8f * attv.w};
    const float4 q = ntld4(xr + (size_t)node * HC + 4 * lane);
    const v2f xa = {q.x, q.y}, xb = {q.z, q.w};
    const int start2 = offs[node] - selfLoop;
    const int total  = deg[node] + selfLoop;

    float l = 0.f;
    v2f Oa = {0.f, 0.f}, Ob = {0.f, 0.f};
    const char* Xc = (const char*)xlh;
    const unsigned laneB = (unsigned)lane * 8u;

    auto ld = [&](int i) -> uint2 {
        int off = (selfLoop && i == 0) ? (node << 9) : ntldi(csr_src + start2 + i);
        return *(const uint2*)(Xc + (unsigned)off + laneB);
    };
    auto process = [&](uint2 w) {
        v2f ca = bfpair(w.x), cb = bfpair(w.y);
        v2f za = ca + xa, zb = cb + xb;
        v2f t = a2a * za + a2b * zb + a8a * vmax0(za) + a8b * vmax0(zb);
        float part = rowsum16(t.x + t.y);
        float p = __expf(fminf(part, 60.f));
        l += p;
        v2f pp = {p, p};
        Oa = pp * ca + Oa;
        Ob = pp * cb + Ob;
    };

    if (total > 0) {
        uint2 b0 = ld(0);
        uint2 b1 = ld(1);
        uint2 b2 = ld(2);
        uint2 b3 = ld(3);
        int i = 0;
        for (; i + 4 <= total; i += 4) {
            uint2 c0 = b0, c1 = b1, c2 = b2, c3 = b3;
            b0 = ld(i + 4);
            b1 = ld(i + 5);
            b2 = ld(i + 6);
            b3 = ld(i + 7);
            process(c0);
            process(c1);
            process(c2);
            process(c3);
        }
        const int rem = total - i;
        if (rem > 0) process(b0);
        if (rem > 1) process(b1);
        if (rem > 2) process(b2);
    }

    float inv = (l > 0.f) ? 0.25f / l : 0.f;
    float vx = Oa.x * inv, vy = Oa.y * inv, vz = Ob.x * inv, vw = Ob.y * inv;
    vx += __shfl_xor(vx, 16); vx += __shfl_xor(vx, 32);
    vy += __shfl_xor(vy, 16); vy += __shfl_xor(vy, 32);
    vz += __shfl_xor(vz, 16); vz += __shfl_xor(vz, 32);
    vw += __shfl_xor(vw, 16); vw += __shfl_xor(vw, 32);

    if (lane < 16) {
        float4 r = make_float4(vx, vy, vz, vw);
        float4* op = (float4*)(out + (size_t)node * OUT_C);
        if (accumulate) {
            float sg = 1.f / (1.f + __expf(-theta[0]));
            float4 cur = op[lane];
            r.x = fmaf(sg, r.x, cur.x);
            r.y = fmaf(sg, r.y, cur.y);
            r.z = fmaf(sg, r.z, cur.z);
            r.w = fmaf(sg, r.w, cur.w);
        }
        op[lane] = r;
    }
}

// ===========================================================================
// Fallback mixed-grid kernels (old VALU path).
// ===========================================================================
__global__ __launch_bounds__(256) void k_mix1(const float* __restrict__ x,
                                              const float* __restrict__ Wa,
                                              ushort_t* __restrict__ oah,
                                              const float* __restrict__ Wb,
                                              float* __restrict__ ob, int n,
                                              int GH, int gG,
                                              const int* __restrict__ dst1, int E1,
                                              const int* __restrict__ dst2, int E2,
                                              int* __restrict__ deg,
                                              int* __restrict__ rank) {
    const int bx = blockIdx.x;
    if (bx < GH) {
        const int Et = E1 + E2;
        for (int i = bx * 256 + threadIdx.x; i < Et; i += GH * 256) {
            if (i < E1) rank[i] = atomicAdd(&deg[dst1[i]], 1);
            else        rank[i] = atomicAdd(&deg[n + dst2[i - E1]], 1);
        }
    } else {
        int t = bx - GH;
        if (t < gG) dev_gemm(x, Wa, nullptr, oah, n, t);
        else        dev_gemm(x, Wb, ob, nullptr, n, t - gG);
    }
}

__global__ __launch_bounds__(256) void k_mix2(const float* __restrict__ x,
                                              const float* __restrict__ Wc,
                                              float* __restrict__ oc, int n,
                                              int GS,
                                              const int* __restrict__ src1,
                                              const int* __restrict__ dst1, int E1,
                                              const int* __restrict__ src2,
                                              const int* __restrict__ dst2, int E2,
                                              const int* __restrict__ offs,
                                              const int* __restrict__ rank,
                                              int* __restrict__ csr) {
    const int bx = blockIdx.x;
    if (bx < GS)
        dev_scatter_rank(src1, dst1, E1, src2, dst2, E2, n, offs, rank, csr, bx, GS);
    else
        dev_gemm(x, Wc, oc, nullptr, n, bx - GS);
}

__global__ __launch_bounds__(256) void k_mix3(const ushort_t* __restrict__ xlh,
                                              const float* __restrict__ xr,
                                              const float* __restrict__ att,
                                              const int* __restrict__ offs,
                                              const int* __restrict__ deg,
                                              const int* __restrict__ csr_src,
                                              int n, float* __restrict__ out,
                                              int selfLoop,
                                              const float* __restrict__ theta,
                                              int accumulate) {
    dev_agg(xlh, xr, att, offs, deg, csr_src, n, out, selfLoop, theta,
            accumulate, blockIdx.x);
}

// ===========================================================================
// Scan chain
// ===========================================================================
__global__ __launch_bounds__(1024) void k_scanA(const int* __restrict__ deg, int n,
                                                int* __restrict__ incl,
                                                int* __restrict__ bsum) {
    __shared__ int sm[1024];
    const int t = threadIdx.x;
    const int i = blockIdx.x * 1024 + t;
    sm[t] = (i < n) ? deg[i] : 0;
    for (int off = 1; off < 1024; off <<= 1) {
        __syncthreads();
        int u = (t >= off) ? sm[t - off] : 0;
        __syncthreads();
        sm[t] += u;
    }
    if (i < n) incl[i] = sm[t];
    if (t == 1023) bsum[blockIdx.x] = sm[1023];
}

__global__ __launch_bounds__(1024) void k_scanB(int* __restrict__ bsum, int nb) {
    __shared__ int sm[1024];
    const int t = threadIdx.x;
    sm[t] = (t < nb) ? bsum[t] : 0;
    for (int off = 1; off < 1024; off <<= 1) {
        __syncthreads();
        int u = (t >= off) ? sm[t - off] : 0;
        __syncthreads();
        sm[t] += u;
    }
    if (t < nb) bsum[t] = sm[t];
}

__global__ void k_scanCf(const int* __restrict__ incl, const int* __restrict__ deg,
                         const int* __restrict__ bsum, int nb, int n,
                         int* __restrict__ offs) {
    __shared__ int sb[128];
    const int t = threadIdx.x;
    if (t < 128) sb[t] = (t < nb) ? bsum[t] : 0;
    __syncthreads();
#pragma unroll
    for (int off = 1; off < 128; off <<= 1) {
        int u = (t >= off && t < 128) ? sb[t - off] : 0;
        __syncthreads();
        if (t < 128) sb[t] += u;
        __syncthreads();
    }
    int i = blockIdx.x * 256 + t;
    if (i < n) {
        int b    = i >> 10;
        int base = (b > 0) ? sb[b - 1] : 0;
        offs[i] = base + incl[i] - deg[i];
    }
}

__global__ void k_scanC(const int* __restrict__ incl, const int* __restrict__ deg,
                        const int* __restrict__ bsum, int n,
                        int* __restrict__ offs) {
    int i = blockIdx.x * 256 + threadIdx.x;
    if (i < n) {
        int b    = i >> 10;
        int base = (b > 0) ? bsum[b - 1] : 0;
        offs[i] = base + incl[i] - deg[i];
    }
}

// ---------------------------------------------------------------------------
extern "C" void kernel_launch(void* const* d_in, const int* in_sizes, int n_in,
                              void* d_out, int out_size, void* d_ws, size_t ws_size,
                              hipStream_t stream) {
    const float* x     = (const float*)d_in[0];
    const int*   e1    = (const int*)d_in[1];
    const int*   e2    = (const int*)d_in[2];
    const float* Wl    = (const float*)d_in[3];
    const float* Wr0   = (const float*)d_in[4];
    const float* Wr1   = (const float*)d_in[5];
    const float* att0  = (const float*)d_in[6];
    const float* att1  = (const float*)d_in[7];
    const float* theta = (const float*)d_in[8];

    const int n  = in_sizes[0] / IN_CH;  // 50000
    const int E1 = in_sizes[1] / 2;
    const int E2 = in_sizes[2] / 2;
    float* out = (float*)d_out;

    char* w = (char*)d_ws;
    auto alloc = [&](size_t bytes) -> char* {
        char* p = w;
        w += (bytes + 255) & ~(size_t)255;
        return p;
    };
    auto al = [](size_t b) -> size_t { return (b + 255) & ~(size_t)255; };

    const int gT = (n + 63) / 64;              // 64-row GEMM tiles
    const size_t projH = (size_t)n * HC * 2;   // bf16 xl
    const size_t projF = (size_t)n * HC * 4;   // f32 xr
    const size_t eB    = (size_t)(E1 + E2) * 4 + 256;  // +64-int tail pad
    const size_t degB  = (size_t)2 * n * 4;
    const size_t xAB   = (size_t)gT * 1024 * 16;   // packed A frags (uint4)
    const size_t WBB   = (size_t)3 * 4 * 16 * 64 * 16;  // packed B frags

    const size_t need3 = al(projH) + 2 * al(projF) + 2 * al(eB) + 3 * al(degB) + 4096;
    const size_t needM = need3 + 2 * al(xAB) + 2 * al(WBB);
    const bool mfmaPath = ws_size >= needM;
    const bool threeBuf = ws_size >= need3;

    ushort_t* xlh = (ushort_t*)alloc(projH);
    float* xr0 = (float*)alloc(projF);
    float* xr1 = threeBuf ? (float*)alloc(projF) : xr0;
    int* csr  = (int*)alloc(eB);
    int* rank = (int*)alloc(eB);
    int* deg  = (int*)alloc(degB);
    int* offs = (int*)alloc(degB);
    int* tmp  = (int*)alloc(degB);
    int* bsum = (int*)alloc(4096);

    const int GH    = 2048;
    const int GS    = 2048;
    const int n2    = 2 * n;
    const int gN2   = (n2 + 255) / 256;
    const int nScan = (n2 + 1023) / 1024;

    if (mfmaPath) {
        uint4* xAh = (uint4*)alloc(xAB);
        uint4* xAl = (uint4*)alloc(xAB);
        uint4* WBh = (uint4*)alloc(WBB);
        uint4* WBl = (uint4*)alloc(WBB);
        const int gPX = gT * 4;          // x-pack blocks (exact)
        const int gPW = 48;              // W-pack blocks (exact: 12288/256)
        const int gP  = gPX + gPW;

        hipMemsetAsync(deg, 0, degB, stream);
        // INTERLEAVED hist+rank || x-split-pack || W-split-pack (+csr pad zero)
        k_hp<<<GH + gP, 256, 0, stream>>>(x, Wl, Wr0, Wr1,
                                          xAh, xAl, WBh, WBl,
                                          n, GH, gP, gPX,
                                          e1 + E1, E1, e2 + E2, E2,
                                          deg, rank, csr + E1 + E2);
        k_scanA<<<nScan, 1024, 0, stream>>>(deg, n2, tmp, bsum);
        if (nScan <= 128) {
            k_scanCf<<<gN2, 256, 0, stream>>>(tmp, deg, bsum, nScan, n2, offs);
        } else {
            k_scanB<<<1, 1024, 0, stream>>>(bsum, nScan);
            k_scanC<<<gN2, 256, 0, stream>>>(tmp, deg, bsum, n2, offs);
        }
        // scatter || MFMA gemm x3 (XCD-congruent tile grouping)
        k_gemm3<<<GS + 3 * gT, 256, 0, stream>>>(xAh, xAl, WBh, WBl,
                                                 xlh, xr0, xr1, n, GS, gT,
                                                 e1, e1 + E1, E1, e2, e2 + E2, E2,
                                                 offs, rank, csr);
        // fused both-hop aggregation: 2 nodes per 128-thread block
        k_aggboth<<<(n + 1) / 2, 128, 0, stream>>>(xlh, xr0, xr1, att0, att1,
                                                   offs, deg, csr, n, out, theta);
        return;
    }

    // ------- fallback: old VALU-GEMM path -------
    const int gG = gT;
    const int GA4 = (n + 3) / 4;
    hipMemsetAsync(deg, 0, degB, stream);
    hipMemsetAsync(csr + E1 + E2, 0, 256, stream);
    k_mix1<<<GH + 2 * gG, 256, 0, stream>>>(x, Wl, xlh, Wr0, xr0, n, GH, gG,
                                            e1 + E1, E1, e2 + E2, E2, deg, rank);
    k_scanA<<<nScan, 1024, 0, stream>>>(deg, n2, tmp, bsum);
    if (nScan <= 128) {
        k_scanCf<<<gN2, 256, 0, stream>>>(tmp, deg, bsum, nScan, n2, offs);
    } else {
        k_scanB<<<1, 1024, 0, stream>>>(bsum, nScan);
        k_scanC<<<gN2, 256, 0, stream>>>(tmp, deg, bsum, n2, offs);
    }

    if (threeBuf) {
        k_mix2<<<GS + gG, 256, 0, stream>>>(x, Wr1, xr1, n, GS,
                                            e1, e1 + E1, E1, e2, e2 + E2, E2,
                                            offs, rank, csr);
        k_aggboth<<<(n + 1) / 2, 128, 0, stream>>>(xlh, xr0, xr1, att0, att1,
                                                   offs, deg, csr, n, out, theta);
    } else {
        k_mix2<<<GS, 256, 0, stream>>>(x, Wr1, xr1, n, GS,
                                       e1, e1 + E1, E1, e2, e2 + E2, E2,
                                       offs, rank, csr);
        k_mix3<<<GA4, 256, 0, stream>>>(xlh, xr0, att0, offs, deg, csr, n, out,
                                        1, theta, 0);
        k_mix2<<<gG, 256, 0, stream>>>(x, Wr1, xr0, n, 0,
                                       (const int*)nullptr, (const int*)nullptr, 0,
                                       (const int*)nullptr, (const int*)nullptr, 0,
                                       (const int*)nullptr, (const int*)nullptr,
                                       (int*)nullptr);
        k_mix3<<<GA4, 256, 0, stream>>>(xlh, xr0, att1, offs + n, deg + n, csr, n, out,
                                        0, theta, 1);
    }
}